// Round 4
// baseline (2435.587 us; speedup 1.0000x reference)
//
#include <hip/hip_runtime.h>
#include <hip/hip_bf16.h>
#include <cstdint>

// ---------------------------------------------------------------------------
// LSTM  B=64 T=512 I=512 H=512
// Phase 0: convert/transpose inputs -> bf16, W_cat^T bf16, b_cat f32,
//          U pre-swizzled into MFMA B-fragment order.
// Phase 1: x_proj GEMM bf16 MFMA, bias folded, output consumer-swizzled.
// Phase 2: persistent recurrence. R12: 32 WGs; each WG runs TWO independent
//          batch-group recurrences (bgA=2*(bid&1), bgB=bgA+1) interleaved,
//          sharing one U-fragment register file (same hidden slice s).
//          Per-bg exchange protocol is the R8/R11-proven MALL scheme,
//          bit-identical: TAGGED u64 words (hi32 = tag t+1, lo32 = packed
//          bf16 col-pair), relaxed agent atomics, data IS the flag.
//
// Why interleave (R11 PMC): per-step 5.74kcyc vs ~1.2kcyc modeled compute;
// the gap is MALL round trip + sleep/retry quantization (full-16-word
// reload rounds whenever any thread's sample is stale). Interleaving fills
// each bg's publish->poll window with the OTHER bg's compute phase, so the
// first sample is issued ~1 phase (~1.5-2kcyc) after publish and lands
// fresh: no sleep, rare retries. Iteration = max(2C, C+R_true) for TWO
// steps' worth of serial chain. Bounded downside: if R_true == R_eff the
// iteration equals today's single-step time.
//   + selective retry: reload ONLY stale words (cuts retry cost + traffic)
//   + split-K MFMA: 2x chains of 8 per n-tile (shortens dependent chain)
// Column convention: c = h_unit*4 + gate   (gate: 0=i,1=f,2=o,3=c)
// ---------------------------------------------------------------------------

typedef __bf16 bf16;
typedef __bf16 bf16x8 __attribute__((ext_vector_type(8)));
typedef float floatx4 __attribute__((ext_vector_type(4)));
typedef uint64_t u64;
typedef uint32_t u32;

#define T_STEPS 512

// ws layout (bytes)
#define XP_OFF     0ull                        // bf16 [T*B*2048] swizzled = 128 MB
#define XBF_OFF    134217728ull                // bf16 [T*B][512]   = 32 MB
#define WCT_OFF    167772160ull                // bf16 [2048][512]  = 2 MB
#define USW_OFF    169869312ull                // bf16 swizzled U B-frags = 2 MB
#define BCAT_OFF   171966464ull                // f32  [2048]
#define HBUF_OFF   171974656ull                // u64 [2][4][16][256] = 256 KB

__device__ inline u32 pack_bf16x2(float a, float b) {
    union { __bf16 h[2]; u32 u; } cv;
    cv.h[0] = (__bf16)a; cv.h[1] = (__bf16)b;
    return cv.u;
}
__device__ inline float bf_lo(u32 w) { return __builtin_bit_cast(float, w << 16); }
__device__ inline float bf_hi(u32 w) { return __builtin_bit_cast(float, w & 0xffff0000u); }

// barrier that waits only LDS (lgkmcnt(0)); global loads/stores stay in flight.
// simm16: vmcnt lo[3:0]=0xF, expcnt[6:4]=7, lgkmcnt[11:8]=0, vmcnt hi[15:14]=3
__device__ inline void lgkm_barrier() {
    __atomic_signal_fence(__ATOMIC_SEQ_CST);
    __builtin_amdgcn_s_waitcnt(0xc07f);
    __builtin_amdgcn_s_barrier();
    __atomic_signal_fence(__ATOMIC_SEQ_CST);
}

// wave-local LDS write->read fence: no s_barrier, just drain LDS ops and pin
// the scheduler.
__device__ inline void wave_lds_fence() {
    __atomic_signal_fence(__ATOMIC_SEQ_CST);
    __builtin_amdgcn_s_waitcnt(0xc07f);
    __builtin_amdgcn_sched_barrier(0);
    __atomic_signal_fence(__ATOMIC_SEQ_CST);
}

// ---------------- K0a: inputs f32 [B][T][I] -> x_bf bf16 in row order (t*64+b)
__global__ void k0a_convert(const float* __restrict__ in, bf16* __restrict__ xbf) {
    int o = blockIdx.x * 256 + threadIdx.x;
    int k = o & 511;
    int r = o >> 9;
    int t = r >> 6, b = r & 63;
    xbf[o] = (bf16)in[(b * 512 + t) * 512 + k];
}

// ---------------- K0b: W_cat^T[c][k] bf16 (c = h*4+gate) and b_cat f32
__global__ void k0b_wcat(const float* __restrict__ Wi, const float* __restrict__ Wf,
                         const float* __restrict__ Wo, const float* __restrict__ Wc,
                         const float* __restrict__ bi, const float* __restrict__ bfv,
                         const float* __restrict__ bo, const float* __restrict__ bc,
                         bf16* __restrict__ wct, float* __restrict__ bcat) {
    int o = blockIdx.x * 256 + threadIdx.x;      // o = c*512 + k
    int k = o & 511;
    int c = o >> 9;
    int h = c >> 2, g = c & 3;
    const float* W = (g == 0) ? Wi : (g == 1) ? Wf : (g == 2) ? Wo : Wc;
    wct[o] = (bf16)W[k * 512 + h];
    if (o < 2048) {
        int hh = o >> 2, gg = o & 3;
        const float* bv = (gg == 0) ? bi : (gg == 1) ? bfv : (gg == 2) ? bo : bc;
        bcat[o] = bv[hh];
    }
}

// ---------------- K0c: U pre-swizzled into B-fragment order for phase 2.
__global__ void k0c_uswz(const float* __restrict__ Ui, const float* __restrict__ Uf,
                         const float* __restrict__ Uo, const float* __restrict__ Uc,
                         bf16* __restrict__ usw) {
    int o = blockIdx.x * 256 + threadIdx.x;      // [0, 1048576)
    int e  = o & 7;
    int l  = (o >> 3) & 63;
    int ks = (o >> 9) & 15;
    int nt = (o >> 13) & 1;
    int w  = (o >> 14) & 3;
    int s  = o >> 16;
    int k = ks * 32 + (l >> 4) * 8 + e;
    int col_local = (2 * w + nt) * 16 + (l & 15);
    int h = s * 32 + (col_local >> 2);
    int g = col_local & 3;
    const float* U = (g == 0) ? Ui : (g == 1) ? Uf : (g == 2) ? Uo : Uc;
    usw[o] = (bf16)U[k * 512 + h];
}

// ---------------- K1: xp = x_bf @ W_cat + b_cat, output SWIZZLED for k2.
__launch_bounds__(256, 2)
__global__ void k1_gemm(const bf16* __restrict__ xbf, const bf16* __restrict__ wct,
                        const float* __restrict__ bcat, bf16* __restrict__ xp) {
    __shared__ bf16 As[128 * 40];
    __shared__ bf16 Bs[128 * 40];
    int tid = threadIdx.x;
    int wid = tid >> 6, lane = tid & 63;
    int q = lane >> 4, m = lane & 15;
    int wr = wid >> 1, wc = wid & 1;
    int br = blockIdx.x & 255, bc = blockIdx.x >> 8;

    floatx4 acc[4][4] = {};

    for (int kk = 0; kk < 16; ++kk) {
        #pragma unroll
        for (int cc = 0; cc < 2; ++cc) {
            int ch = tid + cc * 256;
            int row = ch >> 2, part = ch & 3;
            bf16x8 va = *(const bf16x8*)&xbf[(br * 128 + row) * 512 + kk * 32 + part * 8];
            bf16x8 vb = *(const bf16x8*)&wct[(bc * 128 + row) * 512 + kk * 32 + part * 8];
            *(bf16x8*)&As[row * 40 + part * 8] = va;
            *(bf16x8*)&Bs[row * 40 + part * 8] = vb;
        }
        __syncthreads();
        bf16x8 af[4], bfr[4];
        #pragma unroll
        for (int i = 0; i < 4; ++i) {
            af[i]  = *(const bf16x8*)&As[(wr * 64 + i * 16 + m) * 40 + q * 8];
            bfr[i] = *(const bf16x8*)&Bs[(wc * 64 + i * 16 + m) * 40 + q * 8];
        }
        #pragma unroll
        for (int mt = 0; mt < 4; ++mt)
            #pragma unroll
            for (int nt = 0; nt < 4; ++nt)
                acc[mt][nt] = __builtin_amdgcn_mfma_f32_16x16x32_bf16(
                    af[mt], bfr[nt], acc[mt][nt], 0, 0, 0);
        __syncthreads();
    }
    float bias[4];
    #pragma unroll
    for (int nt = 0; nt < 4; ++nt) bias[nt] = bcat[bc * 128 + wc * 64 + nt * 16 + m];
    #pragma unroll
    for (int mt = 0; mt < 4; ++mt) {
        #pragma unroll
        for (int nt = 0; nt < 4; ++nt) {
            u32 p0 = pack_bf16x2(acc[mt][nt][0] + bias[nt], acc[mt][nt][1] + bias[nt]);
            u32 p1 = pack_bf16x2(acc[mt][nt][2] + bias[nt], acc[mt][nt][3] + bias[nt]);
            size_t idx = (((((size_t)(br * 2 + wr) * 4 + mt) * 16 + bc) * 8
                           + wc * 4 + nt) * 64 + lane) * 4;
            uint2 v; v.x = p0; v.y = p1;
            *(uint2*)&xp[idx] = v;
        }
    }
}

// ---------------- K2: persistent recurrence, 2-way bg interleave.
// hbuf: u64[2][4][16][256]; word (par,bg,row,pc): hi32 = tag t+1, lo32 =
// packed bf16 col-pair. Store parity t&1, read (t-1)&1. Per-bg protocol is
// the R8/R11-proven one; the two bgs of a WG just alternate phases.
__launch_bounds__(256, 1)
__global__ void k2_rec(const bf16* __restrict__ xp, const bf16* __restrict__ usw,
                       u64* __restrict__ hbuf, float* __restrict__ out) {
    // h staging: [phase p][parity][16 rows x 256 words], rows stride 1024B,
    // 16B chunks XOR-swizzled by (row&7). 64 KB.
    __shared__ u32 h_sh[2][2][16 * 256];
    // per-wave gate slab (reused by both phases; wave-fenced within a phase)
    __shared__ float g_slab[4][16 * 36];

    int tid = threadIdx.x;
    int wid = tid >> 6, lane = tid & 63;
    int q = lane >> 4, m = lane & 15;
    int bid = blockIdx.x;                         // 0..31
    int s   = bid >> 1;                           // hidden slice 0..15
    int bgA = (bid & 1) * 2;                      // phases: p=0 -> bgA, p=1 -> bgA+1

    // U B-fragments in registers -- SHARED by both bg phases (same slice s)
    bf16x8 bfr[2][16];
    {
        const bf16x8* base = (const bf16x8*)usw;
        #pragma unroll
        for (int nt = 0; nt < 2; ++nt)
            #pragma unroll
            for (int ks = 0; ks < 16; ++ks)
                bfr[nt][ks] = base[(((s * 4 + wid) * 2 + nt) * 16 + ks) * 64 + lane];
    }

    // gate/publish identity: row r2, unit pair kk2 within the wave's 8 units
    int r2 = lane >> 2;                            // 0..15
    int kk2 = lane & 3;                            // 0..3
    float cs0[2] = {0.f, 0.f}, cs1[2] = {0.f, 0.f};

    // h_sh write swizzle constants
    int wc = tid >> 2, wk = tid & 3;

    float* gs = &g_slab[wid][0];

    // prefetch xp for t=0, both phases
    uint2 vxa[2], vxb[2];
    #pragma unroll
    for (int p = 0; p < 2; ++p) {
        size_t b0 = ((((size_t)(bgA + p) * 16 + s) * 8 + wid * 2) * 64 + lane) * 4;
        vxa[p] = *(const uint2*)&xp[b0];
        vxb[p] = *(const uint2*)&xp[b0 + 256];
    }

    for (int t = 0; t < T_STEPS; ++t) {
        #pragma unroll
        for (int p = 0; p < 2; ++p) {
            int bg = bgA + p;
            floatx4 acc[2];

            // unpack the xp prefetch (issued one phase-pair ago; retired)
            acc[0][0] = bf_lo(vxa[p].x); acc[0][1] = bf_hi(vxa[p].x);
            acc[0][2] = bf_lo(vxa[p].y); acc[0][3] = bf_hi(vxa[p].y);
            acc[1][0] = bf_lo(vxb[p].x); acc[1][1] = bf_hi(vxb[p].x);
            acc[1][2] = bf_lo(vxb[p].y); acc[1][3] = bf_hi(vxb[p].y);

            if (t > 0) {
                // Poll: first sample issued ~1 phase after this bg's publish
                // (the other bg's compute filled the visibility window), so
                // no pre-poll sleep. Retries reload ONLY stale words.
                const u64* rb = hbuf + ((size_t)((t - 1) & 1) * 4 + bg) * 4096;
                u32 tg = (u32)t;
                u64 w[16];
                #pragma unroll
                for (int i = 0; i < 16; ++i)
                    w[i] = __hip_atomic_load(rb + tid + 256 * i, __ATOMIC_RELAXED,
                                             __HIP_MEMORY_SCOPE_AGENT);
                for (;;) {
                    bool ok = true;
                    #pragma unroll
                    for (int i = 0; i < 16; ++i) ok &= ((u32)(w[i] >> 32) == tg);
                    if (ok) break;
                    #pragma unroll
                    for (int i = 0; i < 16; ++i)
                        if ((u32)(w[i] >> 32) != tg)
                            w[i] = __hip_atomic_load(rb + tid + 256 * i, __ATOMIC_RELAXED,
                                                     __HIP_MEMORY_SCOPE_AGENT);
                }
                // stage h into this phase's parity buffer with XOR-swizzle
                u32* hp = &h_sh[p][(t & 1) ^ 1][0];
                #pragma unroll
                for (int i = 0; i < 16; ++i)
                    hp[i * 256 + ((wc ^ (i & 7)) << 2) + wk] = (u32)w[i];
                lgkm_barrier();                   // one barrier per phase
                const bf16* hbs = (const bf16*)hp;
                // split-K: two chains of 8 per n-tile (shorter dep chain)
                floatx4 accb0 = {}, accb1 = {};
                #pragma unroll
                for (int ks = 0; ks < 8; ++ks) {
                    bf16x8 af = *(const bf16x8*)&hbs[m * 512 + (((4 * ks + q) ^ (m & 7)) << 3)];
                    acc[0] = __builtin_amdgcn_mfma_f32_16x16x32_bf16(af, bfr[0][ks], acc[0], 0, 0, 0);
                    acc[1] = __builtin_amdgcn_mfma_f32_16x16x32_bf16(af, bfr[1][ks], acc[1], 0, 0, 0);
                }
                #pragma unroll
                for (int ks = 8; ks < 16; ++ks) {
                    bf16x8 af = *(const bf16x8*)&hbs[m * 512 + (((4 * ks + q) ^ (m & 7)) << 3)];
                    accb0 = __builtin_amdgcn_mfma_f32_16x16x32_bf16(af, bfr[0][ks], accb0, 0, 0, 0);
                    accb1 = __builtin_amdgcn_mfma_f32_16x16x32_bf16(af, bfr[1][ks], accb1, 0, 0, 0);
                }
                acc[0] += accb0;
                acc[1] += accb1;
            }

            // prefetch next step's xp for this phase NOW; retires during the
            // other phase + wait windows, off the critical path.
            if (t + 1 < T_STEPS) {
                size_t b0 = (((((size_t)(t + 1) * 4 + bg) * 16 + s) * 8 + wid * 2) * 64 + lane) * 4;
                vxa[p] = *(const uint2*)&xp[b0];
                vxb[p] = *(const uint2*)&xp[b0 + 256];
            }

            // wave-private gate staging (transpose acc -> per-unit quads)
            #pragma unroll
            for (int nt = 0; nt < 2; ++nt)
                #pragma unroll
                for (int rr = 0; rr < 4; ++rr)
                    gs[(q * 4 + rr) * 36 + nt * 16 + m] = acc[nt][rr];
            wave_lds_fence();                      // no s_barrier needed

            floatx4 ga = *(const floatx4*)&gs[r2 * 36 + kk2 * 8];
            floatx4 gb = *(const floatx4*)&gs[r2 * 36 + kk2 * 8 + 4];
            float h0, h1;
            {
                float ig = 1.f / (1.f + __expf(-ga[0]));
                float fg = 1.f / (1.f + __expf(-ga[1]));
                float og = 1.f / (1.f + __expf(-ga[2]));
                float th = 1.f - 2.f / (__expf(2.f * ga[3]) + 1.f);
                cs0[p] = fg * cs0[p] + ig * th;
                h0 = og * (1.f - 2.f / (__expf(2.f * cs0[p]) + 1.f));
            }
            {
                float ig = 1.f / (1.f + __expf(-gb[0]));
                float fg = 1.f / (1.f + __expf(-gb[1]));
                float og = 1.f / (1.f + __expf(-gb[2]));
                float th = 1.f - 2.f / (__expf(2.f * gb[3]) + 1.f);
                cs1[p] = fg * cs1[p] + ig * th;
                h1 = og * (1.f - 2.f / (__expf(2.f * cs1[p]) + 1.f));
            }
            // per-wave tagged publish, fire-and-forget
            u64 word = ((u64)(u32)(t + 1) << 32) | (u64)pack_bf16x2(h0, h1);
            __hip_atomic_store(hbuf + (((size_t)(t & 1) * 4 + bg) * 16 + r2) * 256
                                    + s * 16 + wid * 4 + kk2,
                               word, __ATOMIC_RELAXED, __HIP_MEMORY_SCOPE_AGENT);
            if (t == T_STEPS - 1) {
                int u0 = s * 32 + wid * 8 + kk2 * 2;
                out[(bg * 16 + r2) * 512 + u0]     = h0;
                out[(bg * 16 + r2) * 512 + u0 + 1] = h1;
            }
        }
    }
}

// ---------------------------------------------------------------------------
extern "C" void kernel_launch(void* const* d_in, const int* in_sizes, int n_in,
                              void* d_out, int out_size, void* d_ws, size_t ws_size,
                              hipStream_t stream) {
    const float* inp = (const float*)d_in[0];
    const float* Wi  = (const float*)d_in[1];
    const float* Wf  = (const float*)d_in[2];
    const float* Wo  = (const float*)d_in[3];
    const float* Wc  = (const float*)d_in[4];
    const float* Ui  = (const float*)d_in[5];
    const float* Uf  = (const float*)d_in[6];
    const float* Uo  = (const float*)d_in[7];
    const float* Uc  = (const float*)d_in[8];
    const float* bi  = (const float*)d_in[9];
    const float* bfv = (const float*)d_in[10];
    const float* bo  = (const float*)d_in[11];
    const float* bc  = (const float*)d_in[12];

    char* ws = (char*)d_ws;
    bf16*  xp    = (bf16*)(ws + XP_OFF);
    bf16*  xbf   = (bf16*)(ws + XBF_OFF);
    bf16*  wct   = (bf16*)(ws + WCT_OFF);
    bf16*  usw   = (bf16*)(ws + USW_OFF);
    float* bcat  = (float*)(ws + BCAT_OFF);
    u64*   hbuf  = (u64*)(ws + HBUF_OFF);

    k0a_convert<<<65536, 256, 0, stream>>>(inp, xbf);
    k0b_wcat<<<4096, 256, 0, stream>>>(Wi, Wf, Wo, Wc, bi, bfv, bo, bc, wct, bcat);
    k0c_uswz<<<4096, 256, 0, stream>>>(Ui, Uf, Uo, Uc, usw);
    k1_gemm<<<4096, 256, 0, stream>>>(xbf, wct, bcat, xp);
    k2_rec<<<32, 256, 0, stream>>>(xp, usw, hbuf, (float*)d_out);
}

// Round 5
// 1477.668 us; speedup vs baseline: 1.6483x; 1.6483x over previous
//
#include <hip/hip_runtime.h>
#include <hip/hip_bf16.h>
#include <cstdint>

// ---------------------------------------------------------------------------
// LSTM  B=64 T=512 I=512 H=512
// Phase 0: convert/transpose inputs -> bf16, W_cat^T bf16, b_cat f32,
//          U pre-swizzled into MFMA B-fragment order.
// Phase 1: x_proj GEMM bf16 MFMA, bias folded, output consumer-swizzled.
// Phase 2: persistent recurrence, 64 WGs = 4 batch-groups x 16 hidden-slices.
//          U slice in registers. h exchanged via TAGGED u64 words (hi32 = tag
//          t+1, lo32 = packed bf16 col-pair), agent scope, data IS the flag.
//
// R13 = R11 structure (proven: single lgkm barrier/step, wave-private gate
//       staging, per-wave publish, XOR-swizzled h staging) + two deltas:
//   1. PUBLISH VIA ATOMIC EXCHANGE (result unused -> global_atomic_swap_x2,
//      no sc0). Theory: R4-R8 showed publish->visibility ~1000cyc with plain
//      agent stores (sample right after publish is ALWAYS stale) -- the
//      store lingers in the write path before committing at the MALL. An
//      RMW executes AT the MALL immediately; if right, the first post-sleep
//      sample succeeds and the 1-2 retry rounds (~700-1500cyc each) vanish.
//      Still fire-and-forget for the producer.
//   2. Split-K MFMA: two independent 8-deep chains per n-tile (+8 VGPRs),
//      ~200cyc off the dependent-MFMA chain.
// (R12's bg-interleave regressed 1.8x: second phase did not hide R; hot
//  dual polls without sleep loaded the MALL and delayed publishes. Dead.)
// Column convention: c = h_unit*4 + gate   (gate: 0=i,1=f,2=o,3=c)
// ---------------------------------------------------------------------------

typedef __bf16 bf16;
typedef __bf16 bf16x8 __attribute__((ext_vector_type(8)));
typedef float floatx4 __attribute__((ext_vector_type(4)));
typedef uint64_t u64;
typedef uint32_t u32;

#define T_STEPS 512

// ws layout (bytes)
#define XP_OFF     0ull                        // bf16 [T*B*2048] swizzled = 128 MB
#define XBF_OFF    134217728ull                // bf16 [T*B][512]   = 32 MB
#define WCT_OFF    167772160ull                // bf16 [2048][512]  = 2 MB
#define USW_OFF    169869312ull                // bf16 swizzled U B-frags = 2 MB
#define BCAT_OFF   171966464ull                // f32  [2048]
#define HBUF_OFF   171974656ull                // u64 [2][4][16][256] = 256 KB

__device__ inline u32 pack_bf16x2(float a, float b) {
    union { __bf16 h[2]; u32 u; } cv;
    cv.h[0] = (__bf16)a; cv.h[1] = (__bf16)b;
    return cv.u;
}
__device__ inline float bf_lo(u32 w) { return __builtin_bit_cast(float, w << 16); }
__device__ inline float bf_hi(u32 w) { return __builtin_bit_cast(float, w & 0xffff0000u); }

// barrier that waits only LDS (lgkmcnt(0)); global loads/stores stay in flight.
// simm16: vmcnt lo[3:0]=0xF, expcnt[6:4]=7, lgkmcnt[11:8]=0, vmcnt hi[15:14]=3
__device__ inline void lgkm_barrier() {
    __atomic_signal_fence(__ATOMIC_SEQ_CST);
    __builtin_amdgcn_s_waitcnt(0xc07f);
    __builtin_amdgcn_s_barrier();
    __atomic_signal_fence(__ATOMIC_SEQ_CST);
}

// wave-local LDS write->read fence: no s_barrier, just drain LDS ops and pin
// the scheduler (rule: compiler won't order cross-lane LDS deps on its own).
__device__ inline void wave_lds_fence() {
    __atomic_signal_fence(__ATOMIC_SEQ_CST);
    __builtin_amdgcn_s_waitcnt(0xc07f);
    __builtin_amdgcn_sched_barrier(0);
    __atomic_signal_fence(__ATOMIC_SEQ_CST);
}

// ---------------- K0a: inputs f32 [B][T][I] -> x_bf bf16 in row order (t*64+b)
__global__ void k0a_convert(const float* __restrict__ in, bf16* __restrict__ xbf) {
    int o = blockIdx.x * 256 + threadIdx.x;
    int k = o & 511;
    int r = o >> 9;
    int t = r >> 6, b = r & 63;
    xbf[o] = (bf16)in[(b * 512 + t) * 512 + k];
}

// ---------------- K0b: W_cat^T[c][k] bf16 (c = h*4+gate) and b_cat f32
__global__ void k0b_wcat(const float* __restrict__ Wi, const float* __restrict__ Wf,
                         const float* __restrict__ Wo, const float* __restrict__ Wc,
                         const float* __restrict__ bi, const float* __restrict__ bfv,
                         const float* __restrict__ bo, const float* __restrict__ bc,
                         bf16* __restrict__ wct, float* __restrict__ bcat) {
    int o = blockIdx.x * 256 + threadIdx.x;      // o = c*512 + k
    int k = o & 511;
    int c = o >> 9;
    int h = c >> 2, g = c & 3;
    const float* W = (g == 0) ? Wi : (g == 1) ? Wf : (g == 2) ? Wo : Wc;
    wct[o] = (bf16)W[k * 512 + h];
    if (o < 2048) {
        int hh = o >> 2, gg = o & 3;
        const float* bv = (gg == 0) ? bi : (gg == 1) ? bfv : (gg == 2) ? bo : bc;
        bcat[o] = bv[hh];
    }
}

// ---------------- K0c: U pre-swizzled into B-fragment order for phase 2.
__global__ void k0c_uswz(const float* __restrict__ Ui, const float* __restrict__ Uf,
                         const float* __restrict__ Uo, const float* __restrict__ Uc,
                         bf16* __restrict__ usw) {
    int o = blockIdx.x * 256 + threadIdx.x;      // [0, 1048576)
    int e  = o & 7;
    int l  = (o >> 3) & 63;
    int ks = (o >> 9) & 15;
    int nt = (o >> 13) & 1;
    int w  = (o >> 14) & 3;
    int s  = o >> 16;
    int k = ks * 32 + (l >> 4) * 8 + e;
    int col_local = (2 * w + nt) * 16 + (l & 15);
    int h = s * 32 + (col_local >> 2);
    int g = col_local & 3;
    const float* U = (g == 0) ? Ui : (g == 1) ? Uf : (g == 2) ? Uo : Uc;
    usw[o] = (bf16)U[k * 512 + h];
}

// ---------------- K1: xp = x_bf @ W_cat + b_cat, output SWIZZLED for k2.
__launch_bounds__(256, 2)
__global__ void k1_gemm(const bf16* __restrict__ xbf, const bf16* __restrict__ wct,
                        const float* __restrict__ bcat, bf16* __restrict__ xp) {
    __shared__ bf16 As[128 * 40];
    __shared__ bf16 Bs[128 * 40];
    int tid = threadIdx.x;
    int wid = tid >> 6, lane = tid & 63;
    int q = lane >> 4, m = lane & 15;
    int wr = wid >> 1, wc = wid & 1;
    int br = blockIdx.x & 255, bc = blockIdx.x >> 8;

    floatx4 acc[4][4] = {};

    for (int kk = 0; kk < 16; ++kk) {
        #pragma unroll
        for (int cc = 0; cc < 2; ++cc) {
            int ch = tid + cc * 256;
            int row = ch >> 2, part = ch & 3;
            bf16x8 va = *(const bf16x8*)&xbf[(br * 128 + row) * 512 + kk * 32 + part * 8];
            bf16x8 vb = *(const bf16x8*)&wct[(bc * 128 + row) * 512 + kk * 32 + part * 8];
            *(bf16x8*)&As[row * 40 + part * 8] = va;
            *(bf16x8*)&Bs[row * 40 + part * 8] = vb;
        }
        __syncthreads();
        bf16x8 af[4], bfr[4];
        #pragma unroll
        for (int i = 0; i < 4; ++i) {
            af[i]  = *(const bf16x8*)&As[(wr * 64 + i * 16 + m) * 40 + q * 8];
            bfr[i] = *(const bf16x8*)&Bs[(wc * 64 + i * 16 + m) * 40 + q * 8];
        }
        #pragma unroll
        for (int mt = 0; mt < 4; ++mt)
            #pragma unroll
            for (int nt = 0; nt < 4; ++nt)
                acc[mt][nt] = __builtin_amdgcn_mfma_f32_16x16x32_bf16(
                    af[mt], bfr[nt], acc[mt][nt], 0, 0, 0);
        __syncthreads();
    }
    float bias[4];
    #pragma unroll
    for (int nt = 0; nt < 4; ++nt) bias[nt] = bcat[bc * 128 + wc * 64 + nt * 16 + m];
    #pragma unroll
    for (int mt = 0; mt < 4; ++mt) {
        #pragma unroll
        for (int nt = 0; nt < 4; ++nt) {
            u32 p0 = pack_bf16x2(acc[mt][nt][0] + bias[nt], acc[mt][nt][1] + bias[nt]);
            u32 p1 = pack_bf16x2(acc[mt][nt][2] + bias[nt], acc[mt][nt][3] + bias[nt]);
            size_t idx = (((((size_t)(br * 2 + wr) * 4 + mt) * 16 + bc) * 8
                           + wc * 4 + nt) * 64 + lane) * 4;
            uint2 v; v.x = p0; v.y = p1;
            *(uint2*)&xp[idx] = v;
        }
    }
}

// ---------------- K2: persistent recurrence (R11 structure; atomic-exchange
// publish; split-K MFMA).
// hbuf: u64[2][4][16][256]; word (par,bg,row,pc): hi32 = tag t+1, lo32 =
// packed bf16 col-pair. Store parity t&1, read (t-1)&1.
__launch_bounds__(256, 1)
__global__ void k2_rec(const bf16* __restrict__ xp, const bf16* __restrict__ usw,
                       u64* __restrict__ hbuf, float* __restrict__ out) {
    // h staging: [parity][row][256 words], rows stride 512 bf16 (1024B), 16B
    // chunks XOR-swizzled by (row&7). 32 KB total.
    __shared__ u32 h_sh[2][16 * 256];
    // per-wave gate slab: [wave][16 rows][36 floats] (stride 36 -> 2-way writes)
    __shared__ float g_slab[4][16 * 36];

    int tid = threadIdx.x;
    int wid = tid >> 6, lane = tid & 63;
    int q = lane >> 4, m = lane & 15;
    int bg = blockIdx.x & 3, s = blockIdx.x >> 2;

    // U B-fragments in registers (one-time, reused all 512 steps)
    bf16x8 bfr[2][16];
    {
        const bf16x8* base = (const bf16x8*)usw;
        #pragma unroll
        for (int nt = 0; nt < 2; ++nt)
            #pragma unroll
            for (int ks = 0; ks < 16; ++ks)
                bfr[nt][ks] = base[(((s * 4 + wid) * 2 + nt) * 16 + ks) * 64 + lane];
    }

    // wave-local gate/publish identity: lane -> (row r2, unit pair kk2).
    int r2 = lane >> 2;                            // 0..15
    int kk2 = lane & 3;                            // 0..3
    float cs0 = 0.f, cs1 = 0.f;

    // h_sh write swizzle constants: write i -> word i*256+((wc^(i&7))<<2)+wk
    int wc = tid >> 2, wk = tid & 3;

    float* gs = &g_slab[wid][0];

    // prefetch xp for t=0
    uint2 vx0, vx1;
    {
        size_t b0 = ((((size_t)bg * 16 + s) * 8 + wid * 2) * 64 + lane) * 4;
        vx0 = *(const uint2*)&xp[b0];
        vx1 = *(const uint2*)&xp[b0 + 256];
    }

    for (int t = 0; t < T_STEPS; ++t) {
        floatx4 acc[2];

        // unpack the xp prefetch (issued last step; retired by now)
        acc[0][0] = bf_lo(vx0.x); acc[0][1] = bf_hi(vx0.x);
        acc[0][2] = bf_lo(vx0.y); acc[0][3] = bf_hi(vx0.y);
        acc[1][0] = bf_lo(vx1.x); acc[1][1] = bf_hi(vx1.x);
        acc[1][2] = bf_lo(vx1.y); acc[1][3] = bf_hi(vx1.y);

        if (t > 0) {
            // calibrated pre-poll delay (~512 cyc): lets the other 15
            // producers' publishes commit at the MALL so the FIRST sample
            // succeeds (R4-R8 evidence).
            __atomic_signal_fence(__ATOMIC_SEQ_CST);
            __builtin_amdgcn_s_sleep(8);
            __atomic_signal_fence(__ATOMIC_SEQ_CST);

            const u64* rb = hbuf + ((size_t)((t - 1) & 1) * 4 + bg) * 4096;
            u32 tg = (u32)t;
            u64 w[16];
            #pragma unroll
            for (int i = 0; i < 16; ++i)
                w[i] = __hip_atomic_load(rb + tid + 256 * i, __ATOMIC_RELAXED,
                                         __HIP_MEMORY_SCOPE_AGENT);
            for (;;) {
                bool ok = true;
                #pragma unroll
                for (int i = 0; i < 16; ++i) ok &= ((u32)(w[i] >> 32) == tg);
                if (ok) break;
                #pragma unroll
                for (int i = 0; i < 16; ++i)
                    w[i] = __hip_atomic_load(rb + tid + 256 * i, __ATOMIC_RELAXED,
                                             __HIP_MEMORY_SCOPE_AGENT);
            }
            // stage h into parity buffer (t-1)&1 with XOR-swizzled chunks
            u32* hp = &h_sh[(t & 1) ^ 1][0];
            #pragma unroll
            for (int i = 0; i < 16; ++i)
                hp[i * 256 + ((wc ^ (i & 7)) << 2) + wk] = (u32)w[i];
            lgkm_barrier();                       // the ONLY barrier per step
            const bf16* hbs = (const bf16*)hp;
            // split-K: two independent 8-deep chains per n-tile
            floatx4 accb0 = {}, accb1 = {};
            #pragma unroll
            for (int ks = 0; ks < 8; ++ks) {
                bf16x8 af = *(const bf16x8*)&hbs[m * 512 + (((4 * ks + q) ^ (m & 7)) << 3)];
                acc[0] = __builtin_amdgcn_mfma_f32_16x16x32_bf16(af, bfr[0][ks], acc[0], 0, 0, 0);
                acc[1] = __builtin_amdgcn_mfma_f32_16x16x32_bf16(af, bfr[1][ks], acc[1], 0, 0, 0);
            }
            #pragma unroll
            for (int ks = 8; ks < 16; ++ks) {
                bf16x8 af = *(const bf16x8*)&hbs[m * 512 + (((4 * ks + q) ^ (m & 7)) << 3)];
                accb0 = __builtin_amdgcn_mfma_f32_16x16x32_bf16(af, bfr[0][ks], accb0, 0, 0, 0);
                accb1 = __builtin_amdgcn_mfma_f32_16x16x32_bf16(af, bfr[1][ks], accb1, 0, 0, 0);
            }
            acc[0] += accb0;
            acc[1] += accb1;
        }

        // prefetch next step's xp NOW; survives the lgkm-only barrier and
        // retires off the critical path.
        if (t + 1 < T_STEPS) {
            size_t b0 = (((((size_t)(t + 1) * 4 + bg) * 16 + s) * 8 + wid * 2) * 64 + lane) * 4;
            vx0 = *(const uint2*)&xp[b0];
            vx1 = *(const uint2*)&xp[b0 + 256];
        }

        // wave-private gate staging: lane (m,q) holds (row q*4+rr, col nt*16+m)
        #pragma unroll
        for (int nt = 0; nt < 2; ++nt)
            #pragma unroll
            for (int rr = 0; rr < 4; ++rr)
                gs[(q * 4 + rr) * 36 + nt * 16 + m] = acc[nt][rr];
        wave_lds_fence();                          // no s_barrier needed

        // gates: lane (r2, units wid*8+2*kk2, +1) -- two aligned b128 reads
        floatx4 ga = *(const floatx4*)&gs[r2 * 36 + kk2 * 8];
        floatx4 gb = *(const floatx4*)&gs[r2 * 36 + kk2 * 8 + 4];
        float h0, h1;
        {
            float ig = 1.f / (1.f + __expf(-ga[0]));
            float fg = 1.f / (1.f + __expf(-ga[1]));
            float og = 1.f / (1.f + __expf(-ga[2]));
            float th = 1.f - 2.f / (__expf(2.f * ga[3]) + 1.f);
            cs0 = fg * cs0 + ig * th;
            h0 = og * (1.f - 2.f / (__expf(2.f * cs0) + 1.f));
        }
        {
            float ig = 1.f / (1.f + __expf(-gb[0]));
            float fg = 1.f / (1.f + __expf(-gb[1]));
            float og = 1.f / (1.f + __expf(-gb[2]));
            float th = 1.f - 2.f / (__expf(2.f * gb[3]) + 1.f);
            cs1 = fg * cs1 + ig * th;
            h1 = og * (1.f - 2.f / (__expf(2.f * cs1) + 1.f));
        }
        // per-wave tagged publish via ATOMIC EXCHANGE (result unused ->
        // no-return swap; commits at the MALL immediately, no WC lingering).
        u64 word = ((u64)(u32)(t + 1) << 32) | (u64)pack_bf16x2(h0, h1);
        (void)__hip_atomic_exchange(
            hbuf + (((size_t)(t & 1) * 4 + bg) * 16 + r2) * 256
                 + s * 16 + wid * 4 + kk2,
            word, __ATOMIC_RELAXED, __HIP_MEMORY_SCOPE_AGENT);
        if (t == T_STEPS - 1) {
            int u0 = s * 32 + wid * 8 + kk2 * 2;
            out[(bg * 16 + r2) * 512 + u0]     = h0;
            out[(bg * 16 + r2) * 512 + u0 + 1] = h1;
        }
    }
}

// ---------------------------------------------------------------------------
extern "C" void kernel_launch(void* const* d_in, const int* in_sizes, int n_in,
                              void* d_out, int out_size, void* d_ws, size_t ws_size,
                              hipStream_t stream) {
    const float* inp = (const float*)d_in[0];
    const float* Wi  = (const float*)d_in[1];
    const float* Wf  = (const float*)d_in[2];
    const float* Wo  = (const float*)d_in[3];
    const float* Wc  = (const float*)d_in[4];
    const float* Ui  = (const float*)d_in[5];
    const float* Uf  = (const float*)d_in[6];
    const float* Uo  = (const float*)d_in[7];
    const float* Uc  = (const float*)d_in[8];
    const float* bi  = (const float*)d_in[9];
    const float* bfv = (const float*)d_in[10];
    const float* bo  = (const float*)d_in[11];
    const float* bc  = (const float*)d_in[12];

    char* ws = (char*)d_ws;
    bf16*  xp    = (bf16*)(ws + XP_OFF);
    bf16*  xbf   = (bf16*)(ws + XBF_OFF);
    bf16*  wct   = (bf16*)(ws + WCT_OFF);
    bf16*  usw   = (bf16*)(ws + USW_OFF);
    float* bcat  = (float*)(ws + BCAT_OFF);
    u64*   hbuf  = (u64*)(ws + HBUF_OFF);

    k0a_convert<<<65536, 256, 0, stream>>>(inp, xbf);
    k0b_wcat<<<4096, 256, 0, stream>>>(Wi, Wf, Wo, Wc, bi, bfv, bo, bc, wct, bcat);
    k0c_uswz<<<4096, 256, 0, stream>>>(Ui, Uf, Uo, Uc, usw);
    k1_gemm<<<4096, 256, 0, stream>>>(xbf, wct, bcat, xp);
    k2_rec<<<64, 256, 0, stream>>>(xp, usw, hbuf, (float*)d_out);
}

// Round 8
// 1460.548 us; speedup vs baseline: 1.6676x; 1.0117x over previous
//
#include <hip/hip_runtime.h>
#include <hip/hip_bf16.h>
#include <cstdint>

// ---------------------------------------------------------------------------
// LSTM  B=64 T=512 I=512 H=512
// Phase 0: convert/transpose inputs -> bf16, W_cat^T bf16, b_cat f32,
//          U pre-swizzled into MFMA B-fragment order.
// Phase 1: x_proj GEMM bf16 MFMA, bias folded, output consumer-swizzled.
// Phase 2: persistent recurrence, 64 WGs = 4 batch-groups x 16 hidden-slices.
//          U slice in registers. h exchanged via TAGGED u64 words (hi32 = tag
//          t+1, lo32 = packed bf16 col-pair), relaxed agent atomics (data IS
//          the flag) -- R8/R11-proven MALL protocol.
//
// R16 = R14 resubmitted verbatim (R14/R15 never ran: container acquisition
//       failures -- infra, not kernel; no liveness risk vs R11/R13).
// R14 = R11 structure + MALL-residency fix + serial-chain riders:
//   1. NON-TEMPORAL xp: k1 stores xp nt, k2 prefetch-loads xp nt (k0a input
//      nt too). Evidence (R11 PMC): k2 WRITE_SIZE 65.6MB == every hbuf
//      publish reaches HBM; FETCH ~6MB over the streams == a few % of polls
//      miss MALL to HBM; xp's 128MB stream is the eviction pressure. nt
//      demotes xp so the 512KB hbuf stays MALL-resident -> lower/steadier
//      poll RT, fewer retries.
//   2. SELECTIVE RETRY: reload only stale words (one straggler no longer
//      costs a full 16-load round).
//   3. rcp GATES: __builtin_amdgcn_rcpf replaces 8 f32 divides/thread
//      (~1ulp; negligible vs bf16 rounding) -- ~100-150cyc off the
//      pre-publish critical path.
//   (R13 post-mortem: atomic-exchange publish = null -> publish-side WC
//    lingering theory dead; reverted to plain agent store. Split-K kept.)
// Column convention: c = h_unit*4 + gate   (gate: 0=i,1=f,2=o,3=c)
// ---------------------------------------------------------------------------

typedef __bf16 bf16;
typedef __bf16 bf16x8 __attribute__((ext_vector_type(8)));
typedef float floatx4 __attribute__((ext_vector_type(4)));
typedef uint64_t u64;
typedef uint32_t u32;

#define T_STEPS 512

// ws layout (bytes)
#define XP_OFF     0ull                        // bf16 [T*B*2048] swizzled = 128 MB
#define XBF_OFF    134217728ull                // bf16 [T*B][512]   = 32 MB
#define WCT_OFF    167772160ull                // bf16 [2048][512]  = 2 MB
#define USW_OFF    169869312ull                // bf16 swizzled U B-frags = 2 MB
#define BCAT_OFF   171966464ull                // f32  [2048]
#define HBUF_OFF   171974656ull                // u64 [2][4][16][256] = 256 KB

__device__ inline u32 pack_bf16x2(float a, float b) {
    union { __bf16 h[2]; u32 u; } cv;
    cv.h[0] = (__bf16)a; cv.h[1] = (__bf16)b;
    return cv.u;
}
__device__ inline float bf_lo(u32 w) { return __builtin_bit_cast(float, w << 16); }
__device__ inline float bf_hi(u32 w) { return __builtin_bit_cast(float, w & 0xffff0000u); }

// fast sigmoid / tanh via v_exp + v_rcp (~1ulp rcp; fine vs bf16 rounding)
__device__ inline float fast_sigmoid(float x) {
    return __builtin_amdgcn_rcpf(1.f + __expf(-x));
}
__device__ inline float fast_tanh(float x) {
    return 1.f - 2.f * __builtin_amdgcn_rcpf(__expf(2.f * x) + 1.f);
}

// barrier that waits only LDS (lgkmcnt(0)); global loads/stores stay in flight.
// simm16: vmcnt lo[3:0]=0xF, expcnt[6:4]=7, lgkmcnt[11:8]=0, vmcnt hi[15:14]=3
__device__ inline void lgkm_barrier() {
    __atomic_signal_fence(__ATOMIC_SEQ_CST);
    __builtin_amdgcn_s_waitcnt(0xc07f);
    __builtin_amdgcn_s_barrier();
    __atomic_signal_fence(__ATOMIC_SEQ_CST);
}

// wave-local LDS write->read fence: no s_barrier, just drain LDS ops and pin
// the scheduler (rule: compiler won't order cross-lane LDS deps on its own).
__device__ inline void wave_lds_fence() {
    __atomic_signal_fence(__ATOMIC_SEQ_CST);
    __builtin_amdgcn_s_waitcnt(0xc07f);
    __builtin_amdgcn_sched_barrier(0);
    __atomic_signal_fence(__ATOMIC_SEQ_CST);
}

// ---------------- K0a: inputs f32 [B][T][I] -> x_bf bf16 in row order (t*64+b)
__global__ void k0a_convert(const float* __restrict__ in, bf16* __restrict__ xbf) {
    int o = blockIdx.x * 256 + threadIdx.x;
    int k = o & 511;
    int r = o >> 9;
    int t = r >> 6, b = r & 63;
    float v = __builtin_nontemporal_load(&in[(b * 512 + t) * 512 + k]);
    xbf[o] = (bf16)v;
}

// ---------------- K0b: W_cat^T[c][k] bf16 (c = h*4+gate) and b_cat f32
__global__ void k0b_wcat(const float* __restrict__ Wi, const float* __restrict__ Wf,
                         const float* __restrict__ Wo, const float* __restrict__ Wc,
                         const float* __restrict__ bi, const float* __restrict__ bfv,
                         const float* __restrict__ bo, const float* __restrict__ bc,
                         bf16* __restrict__ wct, float* __restrict__ bcat) {
    int o = blockIdx.x * 256 + threadIdx.x;      // o = c*512 + k
    int k = o & 511;
    int c = o >> 9;
    int h = c >> 2, g = c & 3;
    const float* W = (g == 0) ? Wi : (g == 1) ? Wf : (g == 2) ? Wo : Wc;
    wct[o] = (bf16)W[k * 512 + h];
    if (o < 2048) {
        int hh = o >> 2, gg = o & 3;
        const float* bv = (gg == 0) ? bi : (gg == 1) ? bfv : (gg == 2) ? bo : bc;
        bcat[o] = bv[hh];
    }
}

// ---------------- K0c: U pre-swizzled into B-fragment order for phase 2.
__global__ void k0c_uswz(const float* __restrict__ Ui, const float* __restrict__ Uf,
                         const float* __restrict__ Uo, const float* __restrict__ Uc,
                         bf16* __restrict__ usw) {
    int o = blockIdx.x * 256 + threadIdx.x;      // [0, 1048576)
    int e  = o & 7;
    int l  = (o >> 3) & 63;
    int ks = (o >> 9) & 15;
    int nt = (o >> 13) & 1;
    int w  = (o >> 14) & 3;
    int s  = o >> 16;
    int k = ks * 32 + (l >> 4) * 8 + e;
    int col_local = (2 * w + nt) * 16 + (l & 15);
    int h = s * 32 + (col_local >> 2);
    int g = col_local & 3;
    const float* U = (g == 0) ? Ui : (g == 1) ? Uf : (g == 2) ? Uo : Uc;
    usw[o] = (bf16)U[k * 512 + h];
}

// ---------------- K1: xp = x_bf @ W_cat + b_cat, output SWIZZLED for k2.
__launch_bounds__(256, 2)
__global__ void k1_gemm(const bf16* __restrict__ xbf, const bf16* __restrict__ wct,
                        const float* __restrict__ bcat, bf16* __restrict__ xp) {
    __shared__ bf16 As[128 * 40];
    __shared__ bf16 Bs[128 * 40];
    int tid = threadIdx.x;
    int wid = tid >> 6, lane = tid & 63;
    int q = lane >> 4, m = lane & 15;
    int wr = wid >> 1, wc = wid & 1;
    int br = blockIdx.x & 255, bc = blockIdx.x >> 8;

    floatx4 acc[4][4] = {};

    for (int kk = 0; kk < 16; ++kk) {
        #pragma unroll
        for (int cc = 0; cc < 2; ++cc) {
            int ch = tid + cc * 256;
            int row = ch >> 2, part = ch & 3;
            bf16x8 va = *(const bf16x8*)&xbf[(br * 128 + row) * 512 + kk * 32 + part * 8];
            bf16x8 vb = *(const bf16x8*)&wct[(bc * 128 + row) * 512 + kk * 32 + part * 8];
            *(bf16x8*)&As[row * 40 + part * 8] = va;
            *(bf16x8*)&Bs[row * 40 + part * 8] = vb;
        }
        __syncthreads();
        bf16x8 af[4], bfr[4];
        #pragma unroll
        for (int i = 0; i < 4; ++i) {
            af[i]  = *(const bf16x8*)&As[(wr * 64 + i * 16 + m) * 40 + q * 8];
            bfr[i] = *(const bf16x8*)&Bs[(wc * 64 + i * 16 + m) * 40 + q * 8];
        }
        #pragma unroll
        for (int mt = 0; mt < 4; ++mt)
            #pragma unroll
            for (int nt = 0; nt < 4; ++nt)
                acc[mt][nt] = __builtin_amdgcn_mfma_f32_16x16x32_bf16(
                    af[mt], bfr[nt], acc[mt][nt], 0, 0, 0);
        __syncthreads();
    }
    float bias[4];
    #pragma unroll
    for (int nt = 0; nt < 4; ++nt) bias[nt] = bcat[bc * 128 + wc * 64 + nt * 16 + m];
    #pragma unroll
    for (int mt = 0; mt < 4; ++mt) {
        #pragma unroll
        for (int nt = 0; nt < 4; ++nt) {
            u32 p0 = pack_bf16x2(acc[mt][nt][0] + bias[nt], acc[mt][nt][1] + bias[nt]);
            u32 p1 = pack_bf16x2(acc[mt][nt][2] + bias[nt], acc[mt][nt][3] + bias[nt]);
            size_t idx = (((((size_t)(br * 2 + wr) * 4 + mt) * 16 + bc) * 8
                           + wc * 4 + nt) * 64 + lane) * 4;
            // nt store: xp must not thrash the MALL (hbuf residency, k2)
            u64 pv = (u64)p0 | ((u64)p1 << 32);
            __builtin_nontemporal_store(pv, (u64*)&xp[idx]);
        }
    }
}

// ---------------- K2: persistent recurrence (R11 structure; nt xp loads;
// selective retry; rcp gates; split-K MFMA).
// hbuf: u64[2][4][16][256]; word (par,bg,row,pc): hi32 = tag t+1, lo32 =
// packed bf16 col-pair. Store parity t&1, read (t-1)&1.
__launch_bounds__(256, 1)
__global__ void k2_rec(const bf16* __restrict__ xp, const bf16* __restrict__ usw,
                       u64* __restrict__ hbuf, float* __restrict__ out) {
    // h staging: [parity][row][256 words], rows stride 512 bf16 (1024B), 16B
    // chunks XOR-swizzled by (row&7). 32 KB total.
    __shared__ u32 h_sh[2][16 * 256];
    // per-wave gate slab: [wave][16 rows][36 floats] (stride 36 -> 2-way writes)
    __shared__ float g_slab[4][16 * 36];

    int tid = threadIdx.x;
    int wid = tid >> 6, lane = tid & 63;
    int q = lane >> 4, m = lane & 15;
    int bg = blockIdx.x & 3, s = blockIdx.x >> 2;

    // U B-fragments in registers (one-time, reused all 512 steps)
    bf16x8 bfr[2][16];
    {
        const bf16x8* base = (const bf16x8*)usw;
        #pragma unroll
        for (int nt = 0; nt < 2; ++nt)
            #pragma unroll
            for (int ks = 0; ks < 16; ++ks)
                bfr[nt][ks] = base[(((s * 4 + wid) * 2 + nt) * 16 + ks) * 64 + lane];
    }

    // wave-local gate/publish identity: lane -> (row r2, unit pair kk2).
    int r2 = lane >> 2;                            // 0..15
    int kk2 = lane & 3;                            // 0..3
    float cs0 = 0.f, cs1 = 0.f;

    // h_sh write swizzle constants: write i -> word i*256+((wc^(i&7))<<2)+wk
    int wc = tid >> 2, wk = tid & 3;

    float* gs = &g_slab[wid][0];

    // prefetch xp for t=0 (nt loads: keep xp out of the MALL's way)
    u64 vx0, vx1;
    {
        size_t b0 = ((((size_t)bg * 16 + s) * 8 + wid * 2) * 64 + lane) * 4;
        vx0 = __builtin_nontemporal_load((const u64*)&xp[b0]);
        vx1 = __builtin_nontemporal_load((const u64*)&xp[b0 + 256]);
    }

    for (int t = 0; t < T_STEPS; ++t) {
        floatx4 acc[2];

        // unpack the xp prefetch (issued last step; retired by now)
        {
            u32 x0 = (u32)vx0, x1 = (u32)(vx0 >> 32);
            u32 x2 = (u32)vx1, x3 = (u32)(vx1 >> 32);
            acc[0][0] = bf_lo(x0); acc[0][1] = bf_hi(x0);
            acc[0][2] = bf_lo(x1); acc[0][3] = bf_hi(x1);
            acc[1][0] = bf_lo(x2); acc[1][1] = bf_hi(x2);
            acc[1][2] = bf_lo(x3); acc[1][3] = bf_hi(x3);
        }

        if (t > 0) {
            // calibrated pre-poll delay (~512 cyc): lets the other 15
            // producers' publishes commit at the MALL so the FIRST sample
            // succeeds (R4-R8 evidence).
            __atomic_signal_fence(__ATOMIC_SEQ_CST);
            __builtin_amdgcn_s_sleep(8);
            __atomic_signal_fence(__ATOMIC_SEQ_CST);

            const u64* rb = hbuf + ((size_t)((t - 1) & 1) * 4 + bg) * 4096;
            u32 tg = (u32)t;
            u64 w[16];
            #pragma unroll
            for (int i = 0; i < 16; ++i)
                w[i] = __hip_atomic_load(rb + tid + 256 * i, __ATOMIC_RELAXED,
                                         __HIP_MEMORY_SCOPE_AGENT);
            for (;;) {
                bool ok = true;
                #pragma unroll
                for (int i = 0; i < 16; ++i) ok &= ((u32)(w[i] >> 32) == tg);
                if (ok) break;
                // selective retry: reload ONLY stale words
                #pragma unroll
                for (int i = 0; i < 16; ++i)
                    if ((u32)(w[i] >> 32) != tg)
                        w[i] = __hip_atomic_load(rb + tid + 256 * i, __ATOMIC_RELAXED,
                                                 __HIP_MEMORY_SCOPE_AGENT);
            }
            // stage h into parity buffer (t-1)&1 with XOR-swizzled chunks
            u32* hp = &h_sh[(t & 1) ^ 1][0];
            #pragma unroll
            for (int i = 0; i < 16; ++i)
                hp[i * 256 + ((wc ^ (i & 7)) << 2) + wk] = (u32)w[i];
            lgkm_barrier();                       // the ONLY barrier per step
            const bf16* hbs = (const bf16*)hp;
            // split-K: two independent 8-deep chains per n-tile
            floatx4 accb0 = {}, accb1 = {};
            #pragma unroll
            for (int ks = 0; ks < 8; ++ks) {
                bf16x8 af = *(const bf16x8*)&hbs[m * 512 + (((4 * ks + q) ^ (m & 7)) << 3)];
                acc[0] = __builtin_amdgcn_mfma_f32_16x16x32_bf16(af, bfr[0][ks], acc[0], 0, 0, 0);
                acc[1] = __builtin_amdgcn_mfma_f32_16x16x32_bf16(af, bfr[1][ks], acc[1], 0, 0, 0);
            }
            #pragma unroll
            for (int ks = 8; ks < 16; ++ks) {
                bf16x8 af = *(const bf16x8*)&hbs[m * 512 + (((4 * ks + q) ^ (m & 7)) << 3)];
                accb0 = __builtin_amdgcn_mfma_f32_16x16x32_bf16(af, bfr[0][ks], accb0, 0, 0, 0);
                accb1 = __builtin_amdgcn_mfma_f32_16x16x32_bf16(af, bfr[1][ks], accb1, 0, 0, 0);
            }
            acc[0] += accb0;
            acc[1] += accb1;
        }

        // prefetch next step's xp NOW (nt); survives the lgkm-only barrier
        // and retires off the critical path.
        if (t + 1 < T_STEPS) {
            size_t b0 = (((((size_t)(t + 1) * 4 + bg) * 16 + s) * 8 + wid * 2) * 64 + lane) * 4;
            vx0 = __builtin_nontemporal_load((const u64*)&xp[b0]);
            vx1 = __builtin_nontemporal_load((const u64*)&xp[b0 + 256]);
        }

        // wave-private gate staging: lane (m,q) holds (row q*4+rr, col nt*16+m)
        #pragma unroll
        for (int nt = 0; nt < 2; ++nt)
            #pragma unroll
            for (int rr = 0; rr < 4; ++rr)
                gs[(q * 4 + rr) * 36 + nt * 16 + m] = acc[nt][rr];
        wave_lds_fence();                          // no s_barrier needed

        // gates: lane (r2, units wid*8+2*kk2, +1) -- two aligned b128 reads
        floatx4 ga = *(const floatx4*)&gs[r2 * 36 + kk2 * 8];
        floatx4 gb = *(const floatx4*)&gs[r2 * 36 + kk2 * 8 + 4];
        float h0, h1;
        {
            float ig = fast_sigmoid(ga[0]);
            float fg = fast_sigmoid(ga[1]);
            float og = fast_sigmoid(ga[2]);
            float th = fast_tanh(ga[3]);
            cs0 = fg * cs0 + ig * th;
            h0 = og * fast_tanh(cs0);
        }
        {
            float ig = fast_sigmoid(gb[0]);
            float fg = fast_sigmoid(gb[1]);
            float og = fast_sigmoid(gb[2]);
            float th = fast_tanh(gb[3]);
            cs1 = fg * cs1 + ig * th;
            h1 = og * fast_tanh(cs1);
        }
        // per-wave tagged publish, fire-and-forget (plain agent store;
        // R13 showed atomic-exchange buys nothing)
        u64 word = ((u64)(u32)(t + 1) << 32) | (u64)pack_bf16x2(h0, h1);
        __hip_atomic_store(hbuf + (((size_t)(t & 1) * 4 + bg) * 16 + r2) * 256
                                + s * 16 + wid * 4 + kk2,
                           word, __ATOMIC_RELAXED, __HIP_MEMORY_SCOPE_AGENT);
        if (t == T_STEPS - 1) {
            int u0 = s * 32 + wid * 8 + kk2 * 2;
            out[(bg * 16 + r2) * 512 + u0]     = h0;
            out[(bg * 16 + r2) * 512 + u0 + 1] = h1;
        }
    }
}

// ---------------------------------------------------------------------------
extern "C" void kernel_launch(void* const* d_in, const int* in_sizes, int n_in,
                              void* d_out, int out_size, void* d_ws, size_t ws_size,
                              hipStream_t stream) {
    const float* inp = (const float*)d_in[0];
    const float* Wi  = (const float*)d_in[1];
    const float* Wf  = (const float*)d_in[2];
    const float* Wo  = (const float*)d_in[3];
    const float* Wc  = (const float*)d_in[4];
    const float* Ui  = (const float*)d_in[5];
    const float* Uf  = (const float*)d_in[6];
    const float* Uo  = (const float*)d_in[7];
    const float* Uc  = (const float*)d_in[8];
    const float* bi  = (const float*)d_in[9];
    const float* bfv = (const float*)d_in[10];
    const float* bo  = (const float*)d_in[11];
    const float* bc  = (const float*)d_in[12];

    char* ws = (char*)d_ws;
    bf16*  xp    = (bf16*)(ws + XP_OFF);
    bf16*  xbf   = (bf16*)(ws + XBF_OFF);
    bf16*  wct   = (bf16*)(ws + WCT_OFF);
    bf16*  usw   = (bf16*)(ws + USW_OFF);
    float* bcat  = (float*)(ws + BCAT_OFF);
    u64*   hbuf  = (u64*)(ws + HBUF_OFF);

    k0a_convert<<<65536, 256, 0, stream>>>(inp, xbf);
    k0b_wcat<<<4096, 256, 0, stream>>>(Wi, Wf, Wo, Wc, bi, bfv, bo, bc, wct, bcat);
    k0c_uswz<<<4096, 256, 0, stream>>>(Ui, Uf, Uo, Uc, usw);
    k1_gemm<<<4096, 256, 0, stream>>>(xbf, wct, bcat, xp);
    k2_rec<<<64, 256, 0, stream>>>(xp, usw, hbuf, (float*)d_out);
}